// Round 3
// baseline (2223.980 us; speedup 1.0000x reference)
//
#include <hip/hip_runtime.h>
#include <math.h>

// ---------------------------------------------------------------------------
// Stacked vanilla RNN (2 layers), SEQ=128 B=64 E=512 H=1024 V=10000.
//   prep:   transpose+split weights to bf16 hi/lo [n][k]; gather x; cast h0.
//   XP0 = x @ W_x0 + b0            (3-pass split-bf16 MFMA GEMM)
//   recur_roles: 3 decoupled role chains (64 WGs each), dataflow-synced via
//     per-(batch-group, slot) producer flags — NO global barrier:
//       L0: h0[t+1] = tanh(XP0[t+1] + h0[t] @ Wh0)   (self-sync among 32 WGs)
//       P : p[s]    = h0[s] @ Wx1 + b1               (polls L0 flags)
//       L1: h1[s]   = tanh(p[s] + h1[s-1] @ Wh1)     (polls P + self flags)
//   logits = H1 @ W_out + b_out    (1-pass bf16 GEMM, supertiled)
// ---------------------------------------------------------------------------

typedef unsigned short u16;
typedef unsigned long long u64;
typedef __bf16 bf16x8 __attribute__((ext_vector_type(8)));
typedef float  f32x4  __attribute__((ext_vector_type(4)));
typedef unsigned int u32x4 __attribute__((ext_vector_type(4)));
typedef u16 u16x8 __attribute__((ext_vector_type(8)));

#define SEQ_ 128
#define B_   64
#define E_   512
#define H_   1024
#define V_   10000
#define VP_  10112
#define ROWS_ (SEQ_*B_)      // 8192
#define BH_  (B_*H_)         // 65536
#define LOGITS_ 81920000     // SEQ*B*V
#define NWG_ 192
#define FPS_ (129*128)       // flags per bg-chain: 129 slots x 128 wave-flags

__device__ __forceinline__ u16 f2bf(float f) {          // RNE f32 -> bf16
  unsigned u = __builtin_bit_cast(unsigned, f);
  u += 0x7fffu + ((u >> 16) & 1u);
  return (u16)(u >> 16);
}
__device__ __forceinline__ float bf2f(u16 h) {
  unsigned u = ((unsigned)h) << 16;
  return __builtin_bit_cast(float, u);
}
__device__ __forceinline__ void st64(void* p, u64 v) {   // write-through store
  __hip_atomic_store((u64*)p, v, __ATOMIC_RELAXED, __HIP_MEMORY_SCOPE_AGENT);
}
__device__ __forceinline__ u64 pk64(float a, float b) {
  return (u64)__builtin_bit_cast(unsigned, a) |
         ((u64)__builtin_bit_cast(unsigned, b) << 32);
}
__device__ __forceinline__ float tanh_fast(float x) {
  // 1 - 2/(e^{2x}+1); saturates correctly via inf/0. ~1e-6 abs err.
  float e = __expf(2.0f * x);
  return 1.0f - 2.0f * __builtin_amdgcn_rcpf(e + 1.0f);
}

// --------------------------- prep kernels ----------------------------------

__global__ __launch_bounds__(256)
void transpose_split(const float* __restrict__ in, u16* __restrict__ outHi,
                     u16* __restrict__ outLo, int K, int N, int NP)
{
  __shared__ float tile[32][33];
  const int n0 = blockIdx.x * 32, k0 = blockIdx.y * 32;
  const int x = threadIdx.x & 31;
  const int y = threadIdx.x >> 5;
  (void)NP;
#pragma unroll
  for (int i = 0; i < 4; ++i) {
    const int r = y * 4 + i;
    const int n = n0 + x;
    tile[r][x] = (n < N) ? in[(size_t)(k0 + r) * N + n] : 0.f;
  }
  __syncthreads();
#pragma unroll
  for (int i = 0; i < 4; ++i) {
    const int r = y * 4 + i;
    const int n = n0 + r;
    const int k = k0 + x;
    const float v = tile[x][r];
    const u16 hb = f2bf(v);
    outHi[(size_t)n * K + k] = hb;
    if (outLo) outLo[(size_t)n * K + k] = f2bf(v - bf2f(hb));
  }
}

__global__ __launch_bounds__(256)
void gather_x(const int* __restrict__ toks, const float* __restrict__ emb,
              u16* __restrict__ XBhi, u16* __restrict__ XBlo)
{
  const int tid = blockIdx.x * 256 + threadIdx.x;
  const int row = tid >> 6;
  const int c8 = (tid & 63) * 8;
  const int tok = toks[row];
  const float* e = emb + (size_t)tok * E_ + c8;
  u16x8 hv, lv;
#pragma unroll
  for (int j = 0; j < 8; ++j) {
    float f = e[j] * 22.627416997969522f;            // sqrt(512)
    u16 hb = f2bf(f);
    hv[j] = hb;
    lv[j] = f2bf(f - bf2f(hb));
  }
  *(u16x8*)(XBhi + (size_t)row * E_ + c8) = hv;
  *(u16x8*)(XBlo + (size_t)row * E_ + c8) = lv;
}

__global__ __launch_bounds__(256)
void hid_cast(const float* __restrict__ h, u16* H0hi, u16* H0lo, u16* H1hi, u16* H1lo)
{
  const int tid = blockIdx.x * 256 + threadIdx.x;
  float v0 = h[tid], v1 = h[BH_ + tid];
  u16 a = f2bf(v0); H0hi[tid] = a; H0lo[tid] = f2bf(v0 - bf2f(a));
  u16 b = f2bf(v1); H1hi[tid] = b; H1lo[tid] = f2bf(v1 - bf2f(b));
}

// --------------------------- generic MFMA GEMM -----------------------------
template<int NPASS>
__global__ __launch_bounds__(256)
void gemm_bf16(const u16* __restrict__ Ahi, const u16* __restrict__ Alo,
               const u16* __restrict__ Bhi, const u16* __restrict__ Blo,
               const float* __restrict__ bias, float* __restrict__ C,
               int K, int Nreal, int ldc, int nbx, int nby)
{
  constexpr int LDT = 40;
  __shared__ u16 lds[(NPASS == 3 ? 4 : 2) * 128 * LDT];
  u16* As  = lds;
  u16* Bs  = lds + 128 * LDT;
  u16* As2 = (NPASS == 3) ? (lds + 2 * 128 * LDT) : lds;
  u16* Bs2 = (NPASS == 3) ? (lds + 3 * 128 * LDT) : lds;

  const int S = 8;
  int bid  = blockIdx.x;
  int scol = bid / (S * nby);
  int rem  = bid - scol * (S * nby);
  int w    = nbx - scol * S; if (w > S) w = S;
  int bx   = scol * S + rem % w;
  int by   = rem / w;
  const int m0 = by * 128, n0 = bx * 128;

  const int tid  = threadIdx.x;
  const int wave = tid >> 6, lane = tid & 63;
  const int wm = (wave & 1) * 64, wn = (wave >> 1) * 64;
  const int lrow = lane & 15, lk = (lane >> 4) * 8;

  f32x4 acc[4][4] = {};

  const int kTiles = K >> 5;
  for (int kt = 0; kt < kTiles; ++kt) {
    const int k0 = kt << 5;
    __syncthreads();
#pragma unroll
    for (int c = tid; c < 512; c += 256) {
      const int row = c >> 2, kq = c & 3;
      const int l = row * LDT + kq * 8;
      *(u32x4*)(As + l) = *(const u32x4*)(Ahi + (size_t)(m0 + row) * K + k0 + kq * 8);
      *(u32x4*)(Bs + l) = *(const u32x4*)(Bhi + (size_t)(n0 + row) * K + k0 + kq * 8);
      if constexpr (NPASS == 3) {
        *(u32x4*)(As2 + l) = *(const u32x4*)(Alo + (size_t)(m0 + row) * K + k0 + kq * 8);
        *(u32x4*)(Bs2 + l) = *(const u32x4*)(Blo + (size_t)(n0 + row) * K + k0 + kq * 8);
      }
    }
    __syncthreads();
    bf16x8 a[4], b[4];
#pragma unroll
    for (int i = 0; i < 4; ++i) {
      a[i] = *(const bf16x8*)(As + (wm + i * 16 + lrow) * LDT + lk);
      b[i] = *(const bf16x8*)(Bs + (wn + i * 16 + lrow) * LDT + lk);
    }
    if constexpr (NPASS == 3) {
      bf16x8 a2[4], b2[4];
#pragma unroll
      for (int i = 0; i < 4; ++i) {
        a2[i] = *(const bf16x8*)(As2 + (wm + i * 16 + lrow) * LDT + lk);
        b2[i] = *(const bf16x8*)(Bs2 + (wn + i * 16 + lrow) * LDT + lk);
      }
#pragma unroll
      for (int mi = 0; mi < 4; ++mi)
#pragma unroll
        for (int ni = 0; ni < 4; ++ni) {
          acc[mi][ni] = __builtin_amdgcn_mfma_f32_16x16x32_bf16(a[mi],  b[ni],  acc[mi][ni], 0, 0, 0);
          acc[mi][ni] = __builtin_amdgcn_mfma_f32_16x16x32_bf16(a[mi],  b2[ni], acc[mi][ni], 0, 0, 0);
          acc[mi][ni] = __builtin_amdgcn_mfma_f32_16x16x32_bf16(a2[mi], b[ni],  acc[mi][ni], 0, 0, 0);
        }
    } else {
#pragma unroll
      for (int mi = 0; mi < 4; ++mi)
#pragma unroll
        for (int ni = 0; ni < 4; ++ni)
          acc[mi][ni] = __builtin_amdgcn_mfma_f32_16x16x32_bf16(a[mi], b[ni], acc[mi][ni], 0, 0, 0);
    }
  }
#pragma unroll
  for (int mi = 0; mi < 4; ++mi)
#pragma unroll
    for (int ni = 0; ni < 4; ++ni)
#pragma unroll
      for (int r = 0; r < 4; ++r) {
        const int row = m0 + wm + mi * 16 + (lane >> 4) * 4 + r;
        const int col = n0 + wn + ni * 16 + lrow;
        if (col < Nreal) {
          float v = acc[mi][ni][r];
          if (bias) v += bias[col];
          C[(size_t)row * ldc + col] = v;
        }
      }
}

// --------------------------- flag sync primitives ---------------------------
// Per-(bg,slot): 128 wave-flags (32 cg x 4 waves), each written once (value 1)
// by its producer wave after draining payload stores. Consumers poll all 128
// with 2 coalesced agent-scope loads per lane (bypass L1/L2 -> L3-coherent).
__device__ __forceinline__ void pollW(const unsigned* f)
{
  const int l = threadIdx.x & 63;
  for (;;) {
    unsigned a = __hip_atomic_load(f + l,      __ATOMIC_RELAXED, __HIP_MEMORY_SCOPE_AGENT);
    unsigned b = __hip_atomic_load(f + l + 64, __ATOMIC_RELAXED, __HIP_MEMORY_SCOPE_AGENT);
    if (__all((a != 0) & (b != 0))) break;
    __builtin_amdgcn_s_sleep(1);
  }
  asm volatile("" ::: "memory");   // keep payload loads below the poll
}
__device__ __forceinline__ void publish(unsigned* f)
{
  asm volatile("s_waitcnt vmcnt(0)" ::: "memory");  // payload at coherent point
  if ((threadIdx.x & 63) == 0)
    __hip_atomic_store(f, 1u, __ATOMIC_RELAXED, __HIP_MEMORY_SCOPE_AGENT);
}

// --------------------------- role GEMM core --------------------------------
// 96 chained MFMAs: acc += Ahi*Bhi + Ahi*Blo + Alo*Bhi over K=1024 (BK=32/8),
// two interleaved accumulators. B from XOR-swizzled LDS, A streamed global.
__device__ __forceinline__ f32x4 gemm96(const u16* __restrict__ Ahi,
                                        const u16* __restrict__ Alo,
                                        const u16* bsp, int xorv, int lk8,
                                        size_t aoff, f32x4 acc0)
{
  f32x4 acc1 = {0.f, 0.f, 0.f, 0.f};
#pragma unroll
  for (int kc = 0; kc < 32; ++kc) {
    bf16x8 ah = *(const bf16x8*)(Ahi + aoff + kc * 32);
    bf16x8 al = *(const bf16x8*)(Alo + aoff + kc * 32);
    bf16x8 bh = *(const bf16x8*)(bsp + ((kc * 32 + lk8) ^ xorv));
    bf16x8 bl = *(const bf16x8*)(bsp + 32768 + ((kc * 32 + lk8) ^ xorv));
    if (kc & 1) {
      acc1 = __builtin_amdgcn_mfma_f32_16x16x32_bf16(bh, ah, acc1, 0, 0, 0);
      acc1 = __builtin_amdgcn_mfma_f32_16x16x32_bf16(bl, ah, acc1, 0, 0, 0);
      acc1 = __builtin_amdgcn_mfma_f32_16x16x32_bf16(bh, al, acc1, 0, 0, 0);
    } else {
      acc0 = __builtin_amdgcn_mfma_f32_16x16x32_bf16(bh, ah, acc0, 0, 0, 0);
      acc0 = __builtin_amdgcn_mfma_f32_16x16x32_bf16(bl, ah, acc0, 0, 0, 0);
      acc0 = __builtin_amdgcn_mfma_f32_16x16x32_bf16(bh, al, acc0, 0, 0, 0);
    }
  }
  return acc0 + acc1;
}

// --------------------------- decoupled recurrence ---------------------------
// 192 WGs (1/CU, 128 KB LDS each): role = wg>>6 (0=L0,1=P,2=L1), idx=wg&63,
// bg = idx>>5 (32-batch half), cg = idx&31 (32-col strip). Wave (wbg,wcg)
// owns a 16b x 16c quadrant. Weight strip hi+lo staged once in swizzled LDS.
__global__ __launch_bounds__(256, 1)
void recur_roles(const u16* __restrict__ Wh0h, const u16* __restrict__ Wh0l,
                 const u16* __restrict__ Wx1h, const u16* __restrict__ Wx1l,
                 const u16* __restrict__ Wh1h, const u16* __restrict__ Wh1l,
                 const float* __restrict__ XP0, const float* __restrict__ b1,
                 float* __restrict__ Pbuf,
                 u16* __restrict__ H0hi, u16* __restrict__ H0lo,
                 u16* __restrict__ H1hi, u16* __restrict__ H1lo,
                 float* __restrict__ final0, float* __restrict__ final1,
                 unsigned* __restrict__ flags)
{
  __shared__ u16 bsm[2 * 32 * 1024];   // 128 KB: [hi/lo][col][k], XOR-swizzled

  const int wg   = blockIdx.x;
  const int role = wg >> 6;
  const int idx  = wg & 63;
  const int bg   = idx >> 5, cg = idx & 31;

  const u16* Bhi = (role == 0) ? Wh0h : (role == 1) ? Wx1h : Wh1h;
  const u16* Blo = (role == 0) ? Wh0l : (role == 1) ? Wx1l : Wh1l;

  const int tid  = threadIdx.x;
  const int wv   = tid >> 6, lane = tid & 63;
  const int wbg  = wv >> 1, wcg = wv & 1;
  const int lb   = lane & 15;
  const int lk8  = (lane >> 4) * 8;

  for (int c = tid; c < 8192; c += 256) {
    const int p   = c >> 12;
    const int cc  = c & 4095;
    const int col = cc >> 7;
    const int k8  = (cc & 127) * 8;
    u32x4 v = *(const u32x4*)((p ? Blo : Bhi) + (size_t)(cg * 32 + col) * H_ + k8);
    *(u32x4*)(bsm + p * 32768 + col * 1024 + (k8 ^ ((col & 7) << 3))) = v;
  }
  __syncthreads();

  const int batch = bg * 32 + wbg * 16 + lb;
  const int c0    = cg * 32 + wcg * 16 + (lk8 >> 1);
  const int colL  = wcg * 16 + lb;
  const int xorv  = (colL & 7) << 3;
  const u16* bsp  = bsm + colL * 1024;
  const size_t aoff = (size_t)batch * H_ + lk8;
  const size_t boff = (size_t)batch * H_ + c0;

  unsigned* flg0 = flags;
  unsigned* flgP = flags + 2 * FPS_;
  unsigned* flg1 = flags + 4 * FPS_;
  const int fme  = cg * 4 + wv;

  if (role == 0) {
    // L0: slot t -> slot t+1, self-synced within bg-group of 32 WGs
    for (int t = 0; t < SEQ_; ++t) {
      f32x4 init = *(const f32x4*)(XP0 + (size_t)t * BH_ + boff);   // prefetch
      if (t >= 1) pollW(flg0 + ((size_t)bg * 129 + t) * 128);
      f32x4 acc = gemm96(H0hi + (size_t)t * BH_, H0lo + (size_t)t * BH_,
                         bsp, xorv, lk8, aoff, init);
      u64 whi = 0, wlo = 0; float hv[4];
#pragma unroll
      for (int r = 0; r < 4; ++r) {
        float v = tanh_fast(acc[r]);
        u16 hb = f2bf(v);
        whi |= (u64)hb << (16 * r);
        wlo |= (u64)f2bf(v - bf2f(hb)) << (16 * r);
        hv[r] = v;
      }
      st64(H0hi + (size_t)(t + 1) * BH_ + boff, whi);
      st64(H0lo + (size_t)(t + 1) * BH_ + boff, wlo);
      if (t == SEQ_ - 1) {
        st64(final0 + boff,     pk64(hv[0], hv[1]));
        st64(final0 + boff + 2, pk64(hv[2], hv[3]));
      }
      publish(flg0 + ((size_t)bg * 129 + (t + 1)) * 128 + fme);
    }
  } else if (role == 1) {
    // P: p[s] = h0[s] @ Wx1 + b1, gated on L0 flags only
    const f32x4 binit = *(const f32x4*)(b1 + c0);
    for (int s = 1; s <= SEQ_; ++s) {
      pollW(flg0 + ((size_t)bg * 129 + s) * 128);
      f32x4 acc = gemm96(H0hi + (size_t)s * BH_, H0lo + (size_t)s * BH_,
                         bsp, xorv, lk8, aoff, binit);
      float* op = Pbuf + (size_t)(s - 1) * BH_ + boff;
      st64(op,     pk64(acc[0], acc[1]));
      st64(op + 2, pk64(acc[2], acc[3]));
      publish(flgP + ((size_t)bg * 129 + s) * 128 + fme);
    }
  } else {
    // L1: h1[s] = tanh(p[s] + h1[s-1] @ Wh1)
    for (int s = 1; s <= SEQ_; ++s) {
      if (s >= 2) pollW(flg1 + ((size_t)bg * 129 + (s - 1)) * 128);
      pollW(flgP + ((size_t)bg * 129 + s) * 128);
      f32x4 init = *(const f32x4*)(Pbuf + (size_t)(s - 1) * BH_ + boff);
      f32x4 acc = gemm96(H1hi + (size_t)(s - 1) * BH_, H1lo + (size_t)(s - 1) * BH_,
                         bsp, xorv, lk8, aoff, init);
      u64 whi = 0, wlo = 0; float hv[4];
#pragma unroll
      for (int r = 0; r < 4; ++r) {
        float v = tanh_fast(acc[r]);
        u16 hb = f2bf(v);
        whi |= (u64)hb << (16 * r);
        wlo |= (u64)f2bf(v - bf2f(hb)) << (16 * r);
        hv[r] = v;
      }
      st64(H1hi + (size_t)s * BH_ + boff, whi);
      st64(H1lo + (size_t)s * BH_ + boff, wlo);
      if (s == SEQ_) {
        st64(final1 + boff,     pk64(hv[0], hv[1]));
        st64(final1 + boff + 2, pk64(hv[2], hv[3]));
      }
      publish(flg1 + ((size_t)bg * 129 + s) * 128 + fme);
    }
  }
}

// --------------------------- launch ----------------------------------------
extern "C" void kernel_launch(void* const* d_in, const int* in_sizes, int n_in,
                              void* d_out, int out_size, void* d_ws, size_t ws_size,
                              hipStream_t stream)
{
  (void)in_sizes; (void)n_in; (void)out_size; (void)ws_size; // needs ~187 MB ws
  const int*   toks = (const int*)d_in[0];
  const float* hid0 = (const float*)d_in[1];
  const float* emb  = (const float*)d_in[2];
  const float* Wx0  = (const float*)d_in[3];
  const float* Wx1  = (const float*)d_in[4];
  const float* Wh   = (const float*)d_in[5];
  const float* bh   = (const float*)d_in[6];
  const float* Wout = (const float*)d_in[7];
  const float* bout = (const float*)d_in[8];
  float* out = (float*)d_out;

  char* ws = (char*)d_ws;
  size_t off = 0;
  auto alloc = [&](size_t bytes) -> void* {
    void* p = ws + off;
    off += (bytes + 255) & ~(size_t)255;
    return p;
  };
  unsigned* flags = (unsigned*)alloc(6 * FPS_ * 4);      // 396 KB
  u16* XBhi  = (u16*)alloc((size_t)ROWS_ * E_ * 2);
  u16* XBlo  = (u16*)alloc((size_t)ROWS_ * E_ * 2);
  u16* Wx0Th = (u16*)alloc((size_t)H_ * E_ * 2);
  u16* Wx0Tl = (u16*)alloc((size_t)H_ * E_ * 2);
  u16* Wx1Th = (u16*)alloc((size_t)H_ * H_ * 2);
  u16* Wx1Tl = (u16*)alloc((size_t)H_ * H_ * 2);
  u16* Wh0Th = (u16*)alloc((size_t)H_ * H_ * 2);
  u16* Wh0Tl = (u16*)alloc((size_t)H_ * H_ * 2);
  u16* Wh1Th = (u16*)alloc((size_t)H_ * H_ * 2);
  u16* Wh1Tl = (u16*)alloc((size_t)H_ * H_ * 2);
  u16* WoutT = (u16*)alloc((size_t)VP_ * H_ * 2);
  float* XP0 = (float*)alloc((size_t)ROWS_ * H_ * 4);
  float* Pbuf= (float*)alloc((size_t)SEQ_ * BH_ * 4);
  u16* H0hi  = (u16*)alloc((size_t)(SEQ_ + 1) * BH_ * 2);
  u16* H0lo  = (u16*)alloc((size_t)(SEQ_ + 1) * BH_ * 2);
  u16* H1hi  = (u16*)alloc((size_t)(SEQ_ + 1) * BH_ * 2);
  u16* H1lo  = (u16*)alloc((size_t)(SEQ_ + 1) * BH_ * 2);

  hipMemsetAsync(flags, 0, 6 * FPS_ * 4, stream);
  transpose_split<<<dim3(H_ / 32, E_ / 32), 256, 0, stream>>>(Wx0, Wx0Th, Wx0Tl, E_, H_, H_);
  transpose_split<<<dim3(H_ / 32, H_ / 32), 256, 0, stream>>>(Wx1, Wx1Th, Wx1Tl, H_, H_, H_);
  transpose_split<<<dim3(H_ / 32, H_ / 32), 256, 0, stream>>>(Wh,           Wh0Th, Wh0Tl, H_, H_, H_);
  transpose_split<<<dim3(H_ / 32, H_ / 32), 256, 0, stream>>>(Wh + H_ * H_, Wh1Th, Wh1Tl, H_, H_, H_);
  transpose_split<<<dim3(VP_ / 32, H_ / 32), 256, 0, stream>>>(Wout, WoutT, nullptr, H_, V_, VP_);
  gather_x<<<ROWS_ * E_ / 8 / 256, 256, 0, stream>>>(toks, emb, XBhi, XBlo);
  hid_cast<<<BH_ / 256, 256, 0, stream>>>(hid0, H0hi, H0lo, H1hi, H1lo);

  // XP0 = x @ W_x0 + b0
  gemm_bf16<3><<<8 * 64, 256, 0, stream>>>(XBhi, XBlo, Wx0Th, Wx0Tl, bh, XP0,
                                           E_, H_, H_, 8, 64);
  // decoupled pipelined recurrence (both layers + Wx1 projection)
  recur_roles<<<NWG_, 256, 0, stream>>>(Wh0Th, Wh0Tl, Wx1Th, Wx1Tl, Wh1Th, Wh1Tl,
                                        XP0, bh + H_, Pbuf,
                                        H0hi, H0lo, H1hi, H1lo,
                                        out + LOGITS_, out + LOGITS_ + BH_, flags);
  // logits = H1 @ W_out + b_out
  gemm_bf16<1><<<79 * 64, 256, 0, stream>>>(H1hi + BH_, nullptr, WoutT, nullptr,
                                            bout, out, H_, V_, V_, 79, 64);
}

// Round 4
// 2027.126 us; speedup vs baseline: 1.0971x; 1.0971x over previous
//
#include <hip/hip_runtime.h>
#include <math.h>

// ---------------------------------------------------------------------------
// Stacked vanilla RNN (2 layers), SEQ=128 B=64 E=512 H=1024 V=10000.
//   prep:   transpose+split weights to bf16 hi/lo [n][k]; gather x; cast h0.
//   XP0 = x @ W_x0 + b0            (3-pass split-bf16 MFMA GEMM)
//   recur_roles: 3 decoupled role chains (64 WGs each), dataflow-synced via
//     per-(batch-group, slot) PER-WG flags (32 words, 2 cache lines):
//       L0: h0[t+1] = tanh(XP0[t+1] + h0[t] @ Wh0)   (self-sync, 32 WGs)
//       P : p[s]    = h0[s] @ Wx1 + b1               (polls L0 flags)
//       L1: h1[s]   = tanh(p[s] + h1[s-1] @ Wh1)     (dual-poll P + self)
//     publish: vmcnt(0) -> syncthreads -> 1 agent store (lane 0).
//     wait: wave0-only coalesced poll + adaptive back-off (anti-hot-spot).
//   logits = H1 @ W_out + b_out    (1-pass bf16 GEMM, supertiled)
// ---------------------------------------------------------------------------

typedef unsigned short u16;
typedef unsigned long long u64;
typedef __bf16 bf16x8 __attribute__((ext_vector_type(8)));
typedef float  f32x4  __attribute__((ext_vector_type(4)));
typedef unsigned int u32x4 __attribute__((ext_vector_type(4)));
typedef u16 u16x8 __attribute__((ext_vector_type(8)));

#define SEQ_ 128
#define B_   64
#define E_   512
#define H_   1024
#define V_   10000
#define VP_  10112
#define ROWS_ (SEQ_*B_)      // 8192
#define BH_  (B_*H_)         // 65536
#define LOGITS_ 81920000     // SEQ*B*V
#define NWG_ 192
#define FPS_ (129*32)        // flags per bg-chain: 129 slots x 32 WG-flags

__device__ __forceinline__ u16 f2bf(float f) {          // RNE f32 -> bf16
  unsigned u = __builtin_bit_cast(unsigned, f);
  u += 0x7fffu + ((u >> 16) & 1u);
  return (u16)(u >> 16);
}
__device__ __forceinline__ float bf2f(u16 h) {
  unsigned u = ((unsigned)h) << 16;
  return __builtin_bit_cast(float, u);
}
__device__ __forceinline__ void st64(void* p, u64 v) {   // write-through store
  __hip_atomic_store((u64*)p, v, __ATOMIC_RELAXED, __HIP_MEMORY_SCOPE_AGENT);
}
__device__ __forceinline__ u64 pk64(float a, float b) {
  return (u64)__builtin_bit_cast(unsigned, a) |
         ((u64)__builtin_bit_cast(unsigned, b) << 32);
}
__device__ __forceinline__ float tanh_fast(float x) {
  float e = __expf(2.0f * x);
  return 1.0f - 2.0f * __builtin_amdgcn_rcpf(e + 1.0f);
}

// --------------------------- prep kernels ----------------------------------

__global__ __launch_bounds__(256)
void transpose_split(const float* __restrict__ in, u16* __restrict__ outHi,
                     u16* __restrict__ outLo, int K, int N, int NP)
{
  __shared__ float tile[32][33];
  const int n0 = blockIdx.x * 32, k0 = blockIdx.y * 32;
  const int x = threadIdx.x & 31;
  const int y = threadIdx.x >> 5;
  (void)NP;
#pragma unroll
  for (int i = 0; i < 4; ++i) {
    const int r = y * 4 + i;
    const int n = n0 + x;
    tile[r][x] = (n < N) ? in[(size_t)(k0 + r) * N + n] : 0.f;
  }
  __syncthreads();
#pragma unroll
  for (int i = 0; i < 4; ++i) {
    const int r = y * 4 + i;
    const int n = n0 + r;
    const int k = k0 + x;
    const float v = tile[x][r];
    const u16 hb = f2bf(v);
    outHi[(size_t)n * K + k] = hb;
    if (outLo) outLo[(size_t)n * K + k] = f2bf(v - bf2f(hb));
  }
}

__global__ __launch_bounds__(256)
void gather_x(const int* __restrict__ toks, const float* __restrict__ emb,
              u16* __restrict__ XBhi, u16* __restrict__ XBlo)
{
  const int tid = blockIdx.x * 256 + threadIdx.x;
  const int row = tid >> 6;
  const int c8 = (tid & 63) * 8;
  const int tok = toks[row];
  const float* e = emb + (size_t)tok * E_ + c8;
  u16x8 hv, lv;
#pragma unroll
  for (int j = 0; j < 8; ++j) {
    float f = e[j] * 22.627416997969522f;            // sqrt(512)
    u16 hb = f2bf(f);
    hv[j] = hb;
    lv[j] = f2bf(f - bf2f(hb));
  }
  *(u16x8*)(XBhi + (size_t)row * E_ + c8) = hv;
  *(u16x8*)(XBlo + (size_t)row * E_ + c8) = lv;
}

__global__ __launch_bounds__(256)
void hid_cast(const float* __restrict__ h, u16* H0hi, u16* H0lo, u16* H1hi, u16* H1lo)
{
  const int tid = blockIdx.x * 256 + threadIdx.x;
  float v0 = h[tid], v1 = h[BH_ + tid];
  u16 a = f2bf(v0); H0hi[tid] = a; H0lo[tid] = f2bf(v0 - bf2f(a));
  u16 b = f2bf(v1); H1hi[tid] = b; H1lo[tid] = f2bf(v1 - bf2f(b));
}

// --------------------------- generic MFMA GEMM -----------------------------
template<int NPASS>
__global__ __launch_bounds__(256)
void gemm_bf16(const u16* __restrict__ Ahi, const u16* __restrict__ Alo,
               const u16* __restrict__ Bhi, const u16* __restrict__ Blo,
               const float* __restrict__ bias, float* __restrict__ C,
               int K, int Nreal, int ldc, int nbx, int nby)
{
  constexpr int LDT = 40;
  __shared__ u16 lds[(NPASS == 3 ? 4 : 2) * 128 * LDT];
  u16* As  = lds;
  u16* Bs  = lds + 128 * LDT;
  u16* As2 = (NPASS == 3) ? (lds + 2 * 128 * LDT) : lds;
  u16* Bs2 = (NPASS == 3) ? (lds + 3 * 128 * LDT) : lds;

  const int S = 8;
  int bid  = blockIdx.x;
  int scol = bid / (S * nby);
  int rem  = bid - scol * (S * nby);
  int w    = nbx - scol * S; if (w > S) w = S;
  int bx   = scol * S + rem % w;
  int by   = rem / w;
  const int m0 = by * 128, n0 = bx * 128;

  const int tid  = threadIdx.x;
  const int wave = tid >> 6, lane = tid & 63;
  const int wm = (wave & 1) * 64, wn = (wave >> 1) * 64;
  const int lrow = lane & 15, lk = (lane >> 4) * 8;

  f32x4 acc[4][4] = {};

  const int kTiles = K >> 5;
  for (int kt = 0; kt < kTiles; ++kt) {
    const int k0 = kt << 5;
    __syncthreads();
#pragma unroll
    for (int c = tid; c < 512; c += 256) {
      const int row = c >> 2, kq = c & 3;
      const int l = row * LDT + kq * 8;
      *(u32x4*)(As + l) = *(const u32x4*)(Ahi + (size_t)(m0 + row) * K + k0 + kq * 8);
      *(u32x4*)(Bs + l) = *(const u32x4*)(Bhi + (size_t)(n0 + row) * K + k0 + kq * 8);
      if constexpr (NPASS == 3) {
        *(u32x4*)(As2 + l) = *(const u32x4*)(Alo + (size_t)(m0 + row) * K + k0 + kq * 8);
        *(u32x4*)(Bs2 + l) = *(const u32x4*)(Blo + (size_t)(n0 + row) * K + k0 + kq * 8);
      }
    }
    __syncthreads();
    bf16x8 a[4], b[4];
#pragma unroll
    for (int i = 0; i < 4; ++i) {
      a[i] = *(const bf16x8*)(As + (wm + i * 16 + lrow) * LDT + lk);
      b[i] = *(const bf16x8*)(Bs + (wn + i * 16 + lrow) * LDT + lk);
    }
    if constexpr (NPASS == 3) {
      bf16x8 a2[4], b2[4];
#pragma unroll
      for (int i = 0; i < 4; ++i) {
        a2[i] = *(const bf16x8*)(As2 + (wm + i * 16 + lrow) * LDT + lk);
        b2[i] = *(const bf16x8*)(Bs2 + (wn + i * 16 + lrow) * LDT + lk);
      }
#pragma unroll
      for (int mi = 0; mi < 4; ++mi)
#pragma unroll
        for (int ni = 0; ni < 4; ++ni) {
          acc[mi][ni] = __builtin_amdgcn_mfma_f32_16x16x32_bf16(a[mi],  b[ni],  acc[mi][ni], 0, 0, 0);
          acc[mi][ni] = __builtin_amdgcn_mfma_f32_16x16x32_bf16(a[mi],  b2[ni], acc[mi][ni], 0, 0, 0);
          acc[mi][ni] = __builtin_amdgcn_mfma_f32_16x16x32_bf16(a2[mi], b[ni],  acc[mi][ni], 0, 0, 0);
        }
    } else {
#pragma unroll
      for (int mi = 0; mi < 4; ++mi)
#pragma unroll
        for (int ni = 0; ni < 4; ++ni)
          acc[mi][ni] = __builtin_amdgcn_mfma_f32_16x16x32_bf16(a[mi], b[ni], acc[mi][ni], 0, 0, 0);
    }
  }
#pragma unroll
  for (int mi = 0; mi < 4; ++mi)
#pragma unroll
    for (int ni = 0; ni < 4; ++ni)
#pragma unroll
      for (int r = 0; r < 4; ++r) {
        const int row = m0 + wm + mi * 16 + (lane >> 4) * 4 + r;
        const int col = n0 + wn + ni * 16 + lrow;
        if (col < Nreal) {
          float v = acc[mi][ni][r];
          if (bias) v += bias[col];
          C[(size_t)row * ldc + col] = v;
        }
      }
}

// --------------------------- flag sync primitives ---------------------------
// Per-(bg,slot): 32 WG-flags packed in 128 B (2 cache lines). Producer WG:
// per-wave vmcnt(0) -> syncthreads -> lane0 agent store. Consumer: wave0 only
// polls (one coalesced 32-word load), adaptive back-off; waves 1-3 park at
// the trailing __syncthreads. Payload reads are plain cached loads (each slot
// address written once per run, read only post-flag; cross-replay stale lines
// are value-identical by determinism).
__device__ __forceinline__ void publishWG(unsigned* f, int wgi)
{
  asm volatile("s_waitcnt vmcnt(0)" ::: "memory");
  __syncthreads();
  if (threadIdx.x == 0)
    __hip_atomic_store(f + wgi, 1u, __ATOMIC_RELAXED, __HIP_MEMORY_SCOPE_AGENT);
}
__device__ __forceinline__ void pollG(const unsigned* f)
{
  if (threadIdx.x < 64) {
    int it = 0;
    for (;;) {
      unsigned v = __hip_atomic_load(f + (threadIdx.x & 31),
                                     __ATOMIC_RELAXED, __HIP_MEMORY_SCOPE_AGENT);
      if (__all(v != 0)) break;
      if (it < 4) __builtin_amdgcn_s_sleep(2);
      else        __builtin_amdgcn_s_sleep(8);
      ++it;
    }
  }
  __syncthreads();
}
__device__ __forceinline__ void pollG2(const unsigned* fA, const unsigned* fB)
{
  if (threadIdx.x < 64) {
    int it = 0;
    bool okA = false, okB = false;
    for (;;) {
      const int l = threadIdx.x & 31;
      if (!okA) okA = __all(__hip_atomic_load(fA + l, __ATOMIC_RELAXED,
                                              __HIP_MEMORY_SCOPE_AGENT) != 0);
      if (!okB) okB = __all(__hip_atomic_load(fB + l, __ATOMIC_RELAXED,
                                              __HIP_MEMORY_SCOPE_AGENT) != 0);
      if (okA && okB) break;
      if (it < 4) __builtin_amdgcn_s_sleep(2);
      else        __builtin_amdgcn_s_sleep(8);
      ++it;
    }
  }
  __syncthreads();
}

// --------------------------- role GEMM core --------------------------------
// 96 MFMAs, 3 independent accumulator chains interleaved at single-MFMA
// granularity (dep-stall mostly hidden at 1 wave/SIMD).
__device__ __forceinline__ f32x4 gemm96(const u16* __restrict__ Ahi,
                                        const u16* __restrict__ Alo,
                                        const u16* bsp, int xorv, int lk8,
                                        size_t aoff, f32x4 acc0)
{
  f32x4 acc1 = {0.f, 0.f, 0.f, 0.f};
  f32x4 acc2 = {0.f, 0.f, 0.f, 0.f};
#pragma unroll
  for (int kc = 0; kc < 32; ++kc) {
    bf16x8 ah = *(const bf16x8*)(Ahi + aoff + kc * 32);
    bf16x8 al = *(const bf16x8*)(Alo + aoff + kc * 32);
    bf16x8 bh = *(const bf16x8*)(bsp + ((kc * 32 + lk8) ^ xorv));
    bf16x8 bl = *(const bf16x8*)(bsp + 32768 + ((kc * 32 + lk8) ^ xorv));
    acc0 = __builtin_amdgcn_mfma_f32_16x16x32_bf16(bh, ah, acc0, 0, 0, 0);
    acc1 = __builtin_amdgcn_mfma_f32_16x16x32_bf16(bl, ah, acc1, 0, 0, 0);
    acc2 = __builtin_amdgcn_mfma_f32_16x16x32_bf16(bh, al, acc2, 0, 0, 0);
  }
  return acc0 + acc1 + acc2;
}

// --------------------------- decoupled recurrence ---------------------------
// 192 WGs (1/CU, 128 KB LDS): role = wg>>6 (0=L0,1=P,2=L1), idx=wg&63,
// bg = idx>>5 (32-batch half), cg = idx&31 (32-col strip). Wave (wbg,wcg)
// owns a 16b x 16c quadrant. Weight strip hi+lo staged once in swizzled LDS.
__global__ __launch_bounds__(256, 1)
void recur_roles(const u16* __restrict__ Wh0h, const u16* __restrict__ Wh0l,
                 const u16* __restrict__ Wx1h, const u16* __restrict__ Wx1l,
                 const u16* __restrict__ Wh1h, const u16* __restrict__ Wh1l,
                 const float* __restrict__ XP0, const float* __restrict__ b1,
                 float* __restrict__ Pbuf,
                 u16* __restrict__ H0hi, u16* __restrict__ H0lo,
                 u16* __restrict__ H1hi, u16* __restrict__ H1lo,
                 float* __restrict__ final0, float* __restrict__ final1,
                 unsigned* __restrict__ flags)
{
  __shared__ u16 bsm[2 * 32 * 1024];   // 128 KB: [hi/lo][col][k], XOR-swizzled

  const int wg   = blockIdx.x;
  const int role = wg >> 6;
  const int idx  = wg & 63;
  const int bg   = idx >> 5, cg = idx & 31;

  const u16* Bhi = (role == 0) ? Wh0h : (role == 1) ? Wx1h : Wh1h;
  const u16* Blo = (role == 0) ? Wh0l : (role == 1) ? Wx1l : Wh1l;

  const int tid  = threadIdx.x;
  const int wv   = tid >> 6, lane = tid & 63;
  const int wbg  = wv >> 1, wcg = wv & 1;
  const int lb   = lane & 15;
  const int lk8  = (lane >> 4) * 8;

  for (int c = tid; c < 8192; c += 256) {
    const int p   = c >> 12;
    const int cc  = c & 4095;
    const int col = cc >> 7;
    const int k8  = (cc & 127) * 8;
    u32x4 v = *(const u32x4*)((p ? Blo : Bhi) + (size_t)(cg * 32 + col) * H_ + k8);
    *(u32x4*)(bsm + p * 32768 + col * 1024 + (k8 ^ ((col & 7) << 3))) = v;
  }
  __syncthreads();

  const int batch = bg * 32 + wbg * 16 + lb;
  const int c0    = cg * 32 + wcg * 16 + (lk8 >> 1);
  const int colL  = wcg * 16 + lb;
  const int xorv  = (colL & 7) << 3;
  const u16* bsp  = bsm + colL * 1024;
  const size_t aoff = (size_t)batch * H_ + lk8;
  const size_t boff = (size_t)batch * H_ + c0;

  unsigned* flg0 = flags;
  unsigned* flgP = flags + 2 * FPS_;
  unsigned* flg1 = flags + 4 * FPS_;

  if (role == 0) {
    for (int t = 0; t < SEQ_; ++t) {
      f32x4 init = *(const f32x4*)(XP0 + (size_t)t * BH_ + boff);   // prefetch
      if (t >= 1) pollG(flg0 + ((size_t)bg * 129 + t) * 32);
      f32x4 acc = gemm96(H0hi + (size_t)t * BH_, H0lo + (size_t)t * BH_,
                         bsp, xorv, lk8, aoff, init);
      u64 whi = 0, wlo = 0; float hv[4];
#pragma unroll
      for (int r = 0; r < 4; ++r) {
        float v = tanh_fast(acc[r]);
        u16 hb = f2bf(v);
        whi |= (u64)hb << (16 * r);
        wlo |= (u64)f2bf(v - bf2f(hb)) << (16 * r);
        hv[r] = v;
      }
      st64(H0hi + (size_t)(t + 1) * BH_ + boff, whi);
      st64(H0lo + (size_t)(t + 1) * BH_ + boff, wlo);
      if (t == SEQ_ - 1) {
        st64(final0 + boff,     pk64(hv[0], hv[1]));
        st64(final0 + boff + 2, pk64(hv[2], hv[3]));
      }
      publishWG(flg0 + ((size_t)bg * 129 + (t + 1)) * 32, cg);
    }
  } else if (role == 1) {
    const f32x4 binit = *(const f32x4*)(b1 + c0);
    for (int s = 1; s <= SEQ_; ++s) {
      pollG(flg0 + ((size_t)bg * 129 + s) * 32);
      f32x4 acc = gemm96(H0hi + (size_t)s * BH_, H0lo + (size_t)s * BH_,
                         bsp, xorv, lk8, aoff, binit);
      float* op = Pbuf + (size_t)(s - 1) * BH_ + boff;
      st64(op,     pk64(acc[0], acc[1]));
      st64(op + 2, pk64(acc[2], acc[3]));
      publishWG(flgP + ((size_t)bg * 129 + s) * 32, cg);
    }
  } else {
    for (int s = 1; s <= SEQ_; ++s) {
      if (s >= 2) pollG2(flgP + ((size_t)bg * 129 + s) * 32,
                         flg1 + ((size_t)bg * 129 + (s - 1)) * 32);
      else        pollG (flgP + ((size_t)bg * 129 + s) * 32);
      f32x4 init = *(const f32x4*)(Pbuf + (size_t)(s - 1) * BH_ + boff);
      f32x4 acc = gemm96(H1hi + (size_t)(s - 1) * BH_, H1lo + (size_t)(s - 1) * BH_,
                         bsp, xorv, lk8, aoff, init);
      u64 whi = 0, wlo = 0; float hv[4];
#pragma unroll
      for (int r = 0; r < 4; ++r) {
        float v = tanh_fast(acc[r]);
        u16 hb = f2bf(v);
        whi |= (u64)hb << (16 * r);
        wlo |= (u64)f2bf(v - bf2f(hb)) << (16 * r);
        hv[r] = v;
      }
      st64(H1hi + (size_t)s * BH_ + boff, whi);
      st64(H1lo + (size_t)s * BH_ + boff, wlo);
      if (s == SEQ_) {
        st64(final1 + boff,     pk64(hv[0], hv[1]));
        st64(final1 + boff + 2, pk64(hv[2], hv[3]));
      }
      publishWG(flg1 + ((size_t)bg * 129 + s) * 32, cg);
    }
  }
}

// --------------------------- launch ----------------------------------------
extern "C" void kernel_launch(void* const* d_in, const int* in_sizes, int n_in,
                              void* d_out, int out_size, void* d_ws, size_t ws_size,
                              hipStream_t stream)
{
  (void)in_sizes; (void)n_in; (void)out_size; (void)ws_size; // needs ~186 MB ws
  const int*   toks = (const int*)d_in[0];
  const float* hid0 = (const float*)d_in[1];
  const float* emb  = (const float*)d_in[2];
  const float* Wx0  = (const float*)d_in[3];
  const float* Wx1  = (const float*)d_in[4];
  const float* Wh   = (const float*)d_in[5];
  const float* bh   = (const float*)d_in[6];
  const float* Wout = (const float*)d_in[7];
  const float* bout = (const float*)d_in[8];
  float* out = (float*)d_out;

  char* ws = (char*)d_ws;
  size_t off = 0;
  auto alloc = [&](size_t bytes) -> void* {
    void* p = ws + off;
    off += (bytes + 255) & ~(size_t)255;
    return p;
  };
  unsigned* flags = (unsigned*)alloc(6 * FPS_ * 4);      // ~99 KB
  u16* XBhi  = (u16*)alloc((size_t)ROWS_ * E_ * 2);
  u16* XBlo  = (u16*)alloc((size_t)ROWS_ * E_ * 2);
  u16* Wx0Th = (u16*)alloc((size_t)H_ * E_ * 2);
  u16* Wx0Tl = (u16*)alloc((size_t)H_ * E_ * 2);
  u16* Wx1Th = (u16*)alloc((size_t)H_ * H_ * 2);
  u16* Wx1Tl = (u16*)alloc((size_t)H_ * H_ * 2);
  u16* Wh0Th = (u16*)alloc((size_t)H_ * H_ * 2);
  u16* Wh0Tl = (u16*)alloc((size_t)H_ * H_ * 2);
  u16* Wh1Th = (u16*)alloc((size_t)H_ * H_ * 2);
  u16* Wh1Tl = (u16*)alloc((size_t)H_ * H_ * 2);
  u16* WoutT = (u16*)alloc((size_t)VP_ * H_ * 2);
  float* XP0 = (float*)alloc((size_t)ROWS_ * H_ * 4);
  float* Pbuf= (float*)alloc((size_t)SEQ_ * BH_ * 4);
  u16* H0hi  = (u16*)alloc((size_t)(SEQ_ + 1) * BH_ * 2);
  u16* H0lo  = (u16*)alloc((size_t)(SEQ_ + 1) * BH_ * 2);
  u16* H1hi  = (u16*)alloc((size_t)(SEQ_ + 1) * BH_ * 2);
  u16* H1lo  = (u16*)alloc((size_t)(SEQ_ + 1) * BH_ * 2);

  hipMemsetAsync(flags, 0, 6 * FPS_ * 4, stream);
  transpose_split<<<dim3(H_ / 32, E_ / 32), 256, 0, stream>>>(Wx0, Wx0Th, Wx0Tl, E_, H_, H_);
  transpose_split<<<dim3(H_ / 32, H_ / 32), 256, 0, stream>>>(Wx1, Wx1Th, Wx1Tl, H_, H_, H_);
  transpose_split<<<dim3(H_ / 32, H_ / 32), 256, 0, stream>>>(Wh,           Wh0Th, Wh0Tl, H_, H_, H_);
  transpose_split<<<dim3(H_ / 32, H_ / 32), 256, 0, stream>>>(Wh + H_ * H_, Wh1Th, Wh1Tl, H_, H_, H_);
  transpose_split<<<dim3(VP_ / 32, H_ / 32), 256, 0, stream>>>(Wout, WoutT, nullptr, H_, V_, VP_);
  gather_x<<<ROWS_ * E_ / 8 / 256, 256, 0, stream>>>(toks, emb, XBhi, XBlo);
  hid_cast<<<BH_ / 256, 256, 0, stream>>>(hid0, H0hi, H0lo, H1hi, H1lo);

  // XP0 = x @ W_x0 + b0
  gemm_bf16<3><<<8 * 64, 256, 0, stream>>>(XBhi, XBlo, Wx0Th, Wx0Tl, bh, XP0,
                                           E_, H_, H_, 8, 64);
  // decoupled pipelined recurrence (both layers + Wx1 projection)
  recur_roles<<<NWG_, 256, 0, stream>>>(Wh0Th, Wh0Tl, Wx1Th, Wx1Tl, Wh1Th, Wh1Tl,
                                        XP0, bh + H_, Pbuf,
                                        H0hi, H0lo, H1hi, H1lo,
                                        out + LOGITS_, out + LOGITS_ + BH_, flags);
  // logits = H1 @ W_out + b_out
  gemm_bf16<1><<<79 * 64, 256, 0, stream>>>(H1hi + BH_, nullptr, WoutT, nullptr,
                                            bout, out, H_, V_, V_, 79, 64);
}

// Round 5
// 1889.685 us; speedup vs baseline: 1.1769x; 1.0727x over previous
//
#include <hip/hip_runtime.h>
#include <math.h>

// ---------------------------------------------------------------------------
// Stacked vanilla RNN (2 layers), SEQ=128 B=64 E=512 H=1024 V=10000.
//   prep:   transpose+split weights to bf16 hi/lo [n][k]; gather x; cast h0.
//   XP0 = x @ W_x0 + b0            (3-pass split-bf16 MFMA GEMM)
//   recur_roles (XCD-local): grid 256, xcd = bid&7 (round-robin heuristic):
//     XCD0/1 = L0 bg0/bg1 (32 WGs each): h0[t+1]=tanh(XP0+h0[t]@Wh0)
//     XCD2/3 = P          : p[s] = h0[s]@Wx1 + b1
//     XCD4/5 = L1         : h1[s] = tanh(p[s] + h1[s-1]@Wh1)
//     XCD6/7 = exit.
//     Each chain's 32 WGs share one L2 -> payload sc1 write-through leaves an
//     L2 copy; self A-loads are L2 hits; self-flags polled with sc0 loads
//     (L1-bypass, L2-read) + every-16th agent-scope escape (placement-robust).
//     Cross-role flags polled agent-scope (pipeline lag only, not rate).
//   logits = H1 @ W_out + b_out    (1-pass bf16 GEMM, supertiled)
// ---------------------------------------------------------------------------

typedef unsigned short u16;
typedef unsigned long long u64;
typedef __bf16 bf16x8 __attribute__((ext_vector_type(8)));
typedef float  f32x4  __attribute__((ext_vector_type(4)));
typedef unsigned int u32x4 __attribute__((ext_vector_type(4)));
typedef u16 u16x8 __attribute__((ext_vector_type(8)));

#define SEQ_ 128
#define B_   64
#define E_   512
#define H_   1024
#define V_   10000
#define VP_  10112
#define ROWS_ (SEQ_*B_)      // 8192
#define BH_  (B_*H_)         // 65536
#define LOGITS_ 81920000     // SEQ*B*V
#define FPS_ (129*32)        // flags per bg-chain: 129 slots x 32 WG-flags

__device__ __forceinline__ u16 f2bf(float f) {          // RNE f32 -> bf16
  unsigned u = __builtin_bit_cast(unsigned, f);
  u += 0x7fffu + ((u >> 16) & 1u);
  return (u16)(u >> 16);
}
__device__ __forceinline__ float bf2f(u16 h) {
  unsigned u = ((unsigned)h) << 16;
  return __builtin_bit_cast(float, u);
}
__device__ __forceinline__ void st64(void* p, u64 v) {   // write-through store
  __hip_atomic_store((u64*)p, v, __ATOMIC_RELAXED, __HIP_MEMORY_SCOPE_AGENT);
}
__device__ __forceinline__ u64 pk64(float a, float b) {
  return (u64)__builtin_bit_cast(unsigned, a) |
         ((u64)__builtin_bit_cast(unsigned, b) << 32);
}
__device__ __forceinline__ float tanh_fast(float x) {
  float e = __expf(2.0f * x);
  return 1.0f - 2.0f * __builtin_amdgcn_rcpf(e + 1.0f);
}
// sc0 load: bypass L1, read (shared, same-XCD) L2. Used only as a fast path;
// correctness is guaranteed by the periodic agent-scope escape in pollL.
__device__ __forceinline__ unsigned ld_sc0(const unsigned* p) {
  unsigned v;
  asm volatile("global_load_dword %0, %1, off sc0\n\t"
               "s_waitcnt vmcnt(0)"
               : "=v"(v) : "v"(p) : "memory");
  return v;
}

// --------------------------- prep kernels ----------------------------------

__global__ __launch_bounds__(256)
void transpose_split(const float* __restrict__ in, u16* __restrict__ outHi,
                     u16* __restrict__ outLo, int K, int N, int NP)
{
  __shared__ float tile[32][33];
  const int n0 = blockIdx.x * 32, k0 = blockIdx.y * 32;
  const int x = threadIdx.x & 31;
  const int y = threadIdx.x >> 5;
  (void)NP;
#pragma unroll
  for (int i = 0; i < 4; ++i) {
    const int r = y * 4 + i;
    const int n = n0 + x;
    tile[r][x] = (n < N) ? in[(size_t)(k0 + r) * N + n] : 0.f;
  }
  __syncthreads();
#pragma unroll
  for (int i = 0; i < 4; ++i) {
    const int r = y * 4 + i;
    const int n = n0 + r;
    const int k = k0 + x;
    const float v = tile[x][r];
    const u16 hb = f2bf(v);
    outHi[(size_t)n * K + k] = hb;
    if (outLo) outLo[(size_t)n * K + k] = f2bf(v - bf2f(hb));
  }
}

__global__ __launch_bounds__(256)
void gather_x(const int* __restrict__ toks, const float* __restrict__ emb,
              u16* __restrict__ XBhi, u16* __restrict__ XBlo)
{
  const int tid = blockIdx.x * 256 + threadIdx.x;
  const int row = tid >> 6;
  const int c8 = (tid & 63) * 8;
  const int tok = toks[row];
  const float* e = emb + (size_t)tok * E_ + c8;
  u16x8 hv, lv;
#pragma unroll
  for (int j = 0; j < 8; ++j) {
    float f = e[j] * 22.627416997969522f;            // sqrt(512)
    u16 hb = f2bf(f);
    hv[j] = hb;
    lv[j] = f2bf(f - bf2f(hb));
  }
  *(u16x8*)(XBhi + (size_t)row * E_ + c8) = hv;
  *(u16x8*)(XBlo + (size_t)row * E_ + c8) = lv;
}

__global__ __launch_bounds__(256)
void hid_cast(const float* __restrict__ h, u16* H0hi, u16* H0lo, u16* H1hi, u16* H1lo)
{
  const int tid = blockIdx.x * 256 + threadIdx.x;
  float v0 = h[tid], v1 = h[BH_ + tid];
  u16 a = f2bf(v0); H0hi[tid] = a; H0lo[tid] = f2bf(v0 - bf2f(a));
  u16 b = f2bf(v1); H1hi[tid] = b; H1lo[tid] = f2bf(v1 - bf2f(b));
}

// --------------------------- generic MFMA GEMM -----------------------------
template<int NPASS>
__global__ __launch_bounds__(256)
void gemm_bf16(const u16* __restrict__ Ahi, const u16* __restrict__ Alo,
               const u16* __restrict__ Bhi, const u16* __restrict__ Blo,
               const float* __restrict__ bias, float* __restrict__ C,
               int K, int Nreal, int ldc, int nbx, int nby)
{
  constexpr int LDT = 40;
  __shared__ u16 lds[(NPASS == 3 ? 4 : 2) * 128 * LDT];
  u16* As  = lds;
  u16* Bs  = lds + 128 * LDT;
  u16* As2 = (NPASS == 3) ? (lds + 2 * 128 * LDT) : lds;
  u16* Bs2 = (NPASS == 3) ? (lds + 3 * 128 * LDT) : lds;

  const int S = 8;
  int bid  = blockIdx.x;
  int scol = bid / (S * nby);
  int rem  = bid - scol * (S * nby);
  int w    = nbx - scol * S; if (w > S) w = S;
  int bx   = scol * S + rem % w;
  int by   = rem / w;
  const int m0 = by * 128, n0 = bx * 128;

  const int tid  = threadIdx.x;
  const int wave = tid >> 6, lane = tid & 63;
  const int wm = (wave & 1) * 64, wn = (wave >> 1) * 64;
  const int lrow = lane & 15, lk = (lane >> 4) * 8;

  f32x4 acc[4][4] = {};

  const int kTiles = K >> 5;
  for (int kt = 0; kt < kTiles; ++kt) {
    const int k0 = kt << 5;
    __syncthreads();
#pragma unroll
    for (int c = tid; c < 512; c += 256) {
      const int row = c >> 2, kq = c & 3;
      const int l = row * LDT + kq * 8;
      *(u32x4*)(As + l) = *(const u32x4*)(Ahi + (size_t)(m0 + row) * K + k0 + kq * 8);
      *(u32x4*)(Bs + l) = *(const u32x4*)(Bhi + (size_t)(n0 + row) * K + k0 + kq * 8);
      if constexpr (NPASS == 3) {
        *(u32x4*)(As2 + l) = *(const u32x4*)(Alo + (size_t)(m0 + row) * K + k0 + kq * 8);
        *(u32x4*)(Bs2 + l) = *(const u32x4*)(Blo + (size_t)(n0 + row) * K + k0 + kq * 8);
      }
    }
    __syncthreads();
    bf16x8 a[4], b[4];
#pragma unroll
    for (int i = 0; i < 4; ++i) {
      a[i] = *(const bf16x8*)(As + (wm + i * 16 + lrow) * LDT + lk);
      b[i] = *(const bf16x8*)(Bs + (wn + i * 16 + lrow) * LDT + lk);
    }
    if constexpr (NPASS == 3) {
      bf16x8 a2[4], b2[4];
#pragma unroll
      for (int i = 0; i < 4; ++i) {
        a2[i] = *(const bf16x8*)(As2 + (wm + i * 16 + lrow) * LDT + lk);
        b2[i] = *(const bf16x8*)(Bs2 + (wn + i * 16 + lrow) * LDT + lk);
      }
#pragma unroll
      for (int mi = 0; mi < 4; ++mi)
#pragma unroll
        for (int ni = 0; ni < 4; ++ni) {
          acc[mi][ni] = __builtin_amdgcn_mfma_f32_16x16x32_bf16(a[mi],  b[ni],  acc[mi][ni], 0, 0, 0);
          acc[mi][ni] = __builtin_amdgcn_mfma_f32_16x16x32_bf16(a[mi],  b2[ni], acc[mi][ni], 0, 0, 0);
          acc[mi][ni] = __builtin_amdgcn_mfma_f32_16x16x32_bf16(a2[mi], b[ni],  acc[mi][ni], 0, 0, 0);
        }
    } else {
#pragma unroll
      for (int mi = 0; mi < 4; ++mi)
#pragma unroll
        for (int ni = 0; ni < 4; ++ni)
          acc[mi][ni] = __builtin_amdgcn_mfma_f32_16x16x32_bf16(a[mi], b[ni], acc[mi][ni], 0, 0, 0);
    }
  }
#pragma unroll
  for (int mi = 0; mi < 4; ++mi)
#pragma unroll
    for (int ni = 0; ni < 4; ++ni)
#pragma unroll
      for (int r = 0; r < 4; ++r) {
        const int row = m0 + wm + mi * 16 + (lane >> 4) * 4 + r;
        const int col = n0 + wn + ni * 16 + lrow;
        if (col < Nreal) {
          float v = acc[mi][ni][r];
          if (bias) v += bias[col];
          C[(size_t)row * ldc + col] = v;
        }
      }
}

// --------------------------- flag sync primitives ---------------------------
// Per-(bg,slot): 32 WG-flags in 2 cache lines. Producer: per-wave vmcnt(0)
// drain -> syncthreads -> lane0 agent store (writes through, leaves L2 copy).
// pollL: same-XCD flags — sc0 loads (L2) + every-16th agent-scope escape so a
// wrong blockIdx->XCD mapping only slows detection, never deadlocks.
// pollR: cross-XCD flags — agent-scope loads every iteration.
__device__ __forceinline__ void publishWG(unsigned* f, int wgi)
{
  asm volatile("s_waitcnt vmcnt(0)" ::: "memory");
  __syncthreads();
  if (threadIdx.x == 0)
    __hip_atomic_store(f + wgi, 1u, __ATOMIC_RELAXED, __HIP_MEMORY_SCOPE_AGENT);
}
__device__ __forceinline__ void pollL(const unsigned* f)
{
  if (threadIdx.x < 64) {
    const int l = threadIdx.x & 31;
    for (int it = 0;; ++it) {
      unsigned v;
      if ((it & 15) == 15)
        v = __hip_atomic_load(f + l, __ATOMIC_RELAXED, __HIP_MEMORY_SCOPE_AGENT);
      else
        v = ld_sc0(f + l);
      if (__all(v != 0)) break;
      __builtin_amdgcn_s_sleep(1);
    }
  }
  __syncthreads();
}
__device__ __forceinline__ void pollR(const unsigned* f)
{
  if (threadIdx.x < 64) {
    const int l = threadIdx.x & 31;
    int it = 0;
    for (;;) {
      unsigned v = __hip_atomic_load(f + l, __ATOMIC_RELAXED,
                                     __HIP_MEMORY_SCOPE_AGENT);
      if (__all(v != 0)) break;
      if (it < 4) __builtin_amdgcn_s_sleep(1);
      else        __builtin_amdgcn_s_sleep(4);
      ++it;
    }
  }
  __syncthreads();
}

// --------------------------- role GEMM core --------------------------------
__device__ __forceinline__ f32x4 gemm96(const u16* __restrict__ Ahi,
                                        const u16* __restrict__ Alo,
                                        const u16* bsp, int xorv, int lk8,
                                        size_t aoff, f32x4 acc0)
{
  f32x4 acc1 = {0.f, 0.f, 0.f, 0.f};
  f32x4 acc2 = {0.f, 0.f, 0.f, 0.f};
#pragma unroll
  for (int kc = 0; kc < 32; ++kc) {
    bf16x8 ah = *(const bf16x8*)(Ahi + aoff + kc * 32);
    bf16x8 al = *(const bf16x8*)(Alo + aoff + kc * 32);
    bf16x8 bh = *(const bf16x8*)(bsp + ((kc * 32 + lk8) ^ xorv));
    bf16x8 bl = *(const bf16x8*)(bsp + 32768 + ((kc * 32 + lk8) ^ xorv));
    acc0 = __builtin_amdgcn_mfma_f32_16x16x32_bf16(bh, ah, acc0, 0, 0, 0);
    acc1 = __builtin_amdgcn_mfma_f32_16x16x32_bf16(bl, ah, acc1, 0, 0, 0);
    acc2 = __builtin_amdgcn_mfma_f32_16x16x32_bf16(bh, al, acc2, 0, 0, 0);
  }
  return acc0 + acc1 + acc2;
}

// --------------------------- XCD-local recurrence ---------------------------
// grid 256 (1 WG/CU): xcd = bid&7, slot = bid>>3 (0..31 = cg).
//   xcd 0/1: L0 bg0/1;  xcd 2/3: P bg0/1;  xcd 4/5: L1 bg0/1;  6/7: exit.
// Wave (wbg,wcg) owns a 16b x 16c quadrant of the WG's 32b x 32c tile.
// Weight strip hi+lo staged once into XOR-swizzled LDS (128 KB).
__global__ __launch_bounds__(256, 1)
void recur_roles(const u16* __restrict__ Wh0h, const u16* __restrict__ Wh0l,
                 const u16* __restrict__ Wx1h, const u16* __restrict__ Wx1l,
                 const u16* __restrict__ Wh1h, const u16* __restrict__ Wh1l,
                 const float* __restrict__ XP0, const float* __restrict__ b1,
                 float* __restrict__ Pbuf,
                 u16* __restrict__ H0hi, u16* __restrict__ H0lo,
                 u16* __restrict__ H1hi, u16* __restrict__ H1lo,
                 float* __restrict__ final0, float* __restrict__ final1,
                 unsigned* __restrict__ flags)
{
  __shared__ u16 bsm[2 * 32 * 1024];   // 128 KB: [hi/lo][col][k], XOR-swizzled

  const int bid  = blockIdx.x;
  const int xcd  = bid & 7;
  if (xcd >= 6) return;                 // 64 spare WGs exit immediately
  const int role = xcd >> 1;            // 0=L0, 1=P, 2=L1
  const int bg   = xcd & 1;
  const int cg   = bid >> 3;            // 0..31 col strip

  const u16* Bhi = (role == 0) ? Wh0h : (role == 1) ? Wx1h : Wh1h;
  const u16* Blo = (role == 0) ? Wh0l : (role == 1) ? Wx1l : Wh1l;

  const int tid  = threadIdx.x;
  const int wv   = tid >> 6, lane = tid & 63;
  const int wbg  = wv >> 1, wcg = wv & 1;
  const int lb   = lane & 15;
  const int lk8  = (lane >> 4) * 8;

  for (int c = tid; c < 8192; c += 256) {
    const int p   = c >> 12;
    const int cc  = c & 4095;
    const int col = cc >> 7;
    const int k8  = (cc & 127) * 8;
    u32x4 v = *(const u32x4*)((p ? Blo : Bhi) + (size_t)(cg * 32 + col) * H_ + k8);
    *(u32x4*)(bsm + p * 32768 + col * 1024 + (k8 ^ ((col & 7) << 3))) = v;
  }
  __syncthreads();

  const int batch = bg * 32 + wbg * 16 + lb;
  const int c0    = cg * 32 + wcg * 16 + (lk8 >> 1);
  const int colL  = wcg * 16 + lb;
  const int xorv  = (colL & 7) << 3;
  const u16* bsp  = bsm + colL * 1024;
  const size_t aoff = (size_t)batch * H_ + lk8;
  const size_t boff = (size_t)batch * H_ + c0;

  unsigned* flg0 = flags;
  unsigned* flgP = flags + 2 * FPS_;
  unsigned* flg1 = flags + 4 * FPS_;

  if (role == 0) {
    for (int t = 0; t < SEQ_; ++t) {
      f32x4 init = *(const f32x4*)(XP0 + (size_t)t * BH_ + boff);   // prefetch
      if (t >= 1) pollL(flg0 + ((size_t)bg * 129 + t) * 32);
      f32x4 acc = gemm96(H0hi + (size_t)t * BH_, H0lo + (size_t)t * BH_,
                         bsp, xorv, lk8, aoff, init);
      u64 whi = 0, wlo = 0; float hv[4];
#pragma unroll
      for (int r = 0; r < 4; ++r) {
        float v = tanh_fast(acc[r]);
        u16 hb = f2bf(v);
        whi |= (u64)hb << (16 * r);
        wlo |= (u64)f2bf(v - bf2f(hb)) << (16 * r);
        hv[r] = v;
      }
      st64(H0hi + (size_t)(t + 1) * BH_ + boff, whi);
      st64(H0lo + (size_t)(t + 1) * BH_ + boff, wlo);
      if (t == SEQ_ - 1) {
        st64(final0 + boff,     pk64(hv[0], hv[1]));
        st64(final0 + boff + 2, pk64(hv[2], hv[3]));
      }
      publishWG(flg0 + ((size_t)bg * 129 + (t + 1)) * 32, cg);
    }
  } else if (role == 1) {
    const f32x4 binit = *(const f32x4*)(b1 + c0);
    for (int s = 1; s <= SEQ_; ++s) {
      pollR(flg0 + ((size_t)bg * 129 + s) * 32);
      f32x4 acc = gemm96(H0hi + (size_t)s * BH_, H0lo + (size_t)s * BH_,
                         bsp, xorv, lk8, aoff, binit);
      float* op = Pbuf + (size_t)(s - 1) * BH_ + boff;
      st64(op,     pk64(acc[0], acc[1]));
      st64(op + 2, pk64(acc[2], acc[3]));
      publishWG(flgP + ((size_t)bg * 129 + s) * 32, cg);
    }
  } else {
    for (int s = 1; s <= SEQ_; ++s) {
      pollR(flgP + ((size_t)bg * 129 + s) * 32);
      if (s >= 2) pollL(flg1 + ((size_t)bg * 129 + (s - 1)) * 32);
      f32x4 init = *(const f32x4*)(Pbuf + (size_t)(s - 1) * BH_ + boff);
      f32x4 acc = gemm96(H1hi + (size_t)(s - 1) * BH_, H1lo + (size_t)(s - 1) * BH_,
                         bsp, xorv, lk8, aoff, init);
      u64 whi = 0, wlo = 0; float hv[4];
#pragma unroll
      for (int r = 0; r < 4; ++r) {
        float v = tanh_fast(acc[r]);
        u16 hb = f2bf(v);
        whi |= (u64)hb << (16 * r);
        wlo |= (u64)f2bf(v - bf2f(hb)) << (16 * r);
        hv[r] = v;
      }
      st64(H1hi + (size_t)s * BH_ + boff, whi);
      st64(H1lo + (size_t)s * BH_ + boff, wlo);
      if (s == SEQ_) {
        st64(final1 + boff,     pk64(hv[0], hv[1]));
        st64(final1 + boff + 2, pk64(hv[2], hv[3]));
      }
      publishWG(flg1 + ((size_t)bg * 129 + s) * 32, cg);
    }
  }
}

// --------------------------- launch ----------------------------------------
extern "C" void kernel_launch(void* const* d_in, const int* in_sizes, int n_in,
                              void* d_out, int out_size, void* d_ws, size_t ws_size,
                              hipStream_t stream)
{
  (void)in_sizes; (void)n_in; (void)out_size; (void)ws_size; // needs ~186 MB ws
  const int*   toks = (const int*)d_in[0];
  const float* hid0 = (const float*)d_in[1];
  const float* emb  = (const float*)d_in[2];
  const float* Wx0  = (const float*)d_in[3];
  const float* Wx1  = (const float*)d_in[4];
  const float* Wh   = (const float*)d_in[5];
  const float* bh   = (const float*)d_in[6];
  const float* Wout = (const float*)d_in[7];
  const float* bout = (const float*)d_in[8];
  float* out = (float*)d_out;

  char* ws = (char*)d_ws;
  size_t off = 0;
  auto alloc = [&](size_t bytes) -> void* {
    void* p = ws + off;
    off += (bytes + 255) & ~(size_t)255;
    return p;
  };
  unsigned* flags = (unsigned*)alloc(6 * FPS_ * 4);      // ~99 KB
  u16* XBhi  = (u16*)alloc((size_t)ROWS_ * E_ * 2);
  u16* XBlo  = (u16*)alloc((size_t)ROWS_ * E_ * 2);
  u16* Wx0Th = (u16*)alloc((size_t)H_ * E_ * 2);
  u16* Wx0Tl = (u16*)alloc((size_t)H_ * E_ * 2);
  u16* Wx1Th = (u16*)alloc((size_t)H_ * H_ * 2);
  u16* Wx1Tl = (u16*)alloc((size_t)H_ * H_ * 2);
  u16* Wh0Th = (u16*)alloc((size_t)H_ * H_ * 2);
  u16* Wh0Tl = (u16*)alloc((size_t)H_ * H_ * 2);
  u16* Wh1Th = (u16*)alloc((size_t)H_ * H_ * 2);
  u16* Wh1Tl = (u16*)alloc((size_t)H_ * H_ * 2);
  u16* WoutT = (u16*)alloc((size_t)VP_ * H_ * 2);
  float* XP0 = (float*)alloc((size_t)ROWS_ * H_ * 4);
  float* Pbuf= (float*)alloc((size_t)SEQ_ * BH_ * 4);
  u16* H0hi  = (u16*)alloc((size_t)(SEQ_ + 1) * BH_ * 2);
  u16* H0lo  = (u16*)alloc((size_t)(SEQ_ + 1) * BH_ * 2);
  u16* H1hi  = (u16*)alloc((size_t)(SEQ_ + 1) * BH_ * 2);
  u16* H1lo  = (u16*)alloc((size_t)(SEQ_ + 1) * BH_ * 2);

  hipMemsetAsync(flags, 0, 6 * FPS_ * 4, stream);
  transpose_split<<<dim3(H_ / 32, E_ / 32), 256, 0, stream>>>(Wx0, Wx0Th, Wx0Tl, E_, H_, H_);
  transpose_split<<<dim3(H_ / 32, H_ / 32), 256, 0, stream>>>(Wx1, Wx1Th, Wx1Tl, H_, H_, H_);
  transpose_split<<<dim3(H_ / 32, H_ / 32), 256, 0, stream>>>(Wh,           Wh0Th, Wh0Tl, H_, H_, H_);
  transpose_split<<<dim3(H_ / 32, H_ / 32), 256, 0, stream>>>(Wh + H_ * H_, Wh1Th, Wh1Tl, H_, H_, H_);
  transpose_split<<<dim3(VP_ / 32, H_ / 32), 256, 0, stream>>>(Wout, WoutT, nullptr, H_, V_, VP_);
  gather_x<<<ROWS_ * E_ / 8 / 256, 256, 0, stream>>>(toks, emb, XBhi, XBlo);
  hid_cast<<<BH_ / 256, 256, 0, stream>>>(hid0, H0hi, H0lo, H1hi, H1lo);

  // XP0 = x @ W_x0 + b0
  gemm_bf16<3><<<8 * 64, 256, 0, stream>>>(XBhi, XBlo, Wx0Th, Wx0Tl, bh, XP0,
                                           E_, H_, H_, 8, 64);
  // XCD-local decoupled recurrence (both layers + Wx1 projection)
  recur_roles<<<256, 256, 0, stream>>>(Wh0Th, Wh0Tl, Wx1Th, Wx1Tl, Wh1Th, Wh1Tl,
                                       XP0, bh + H_, Pbuf,
                                       H0hi, H0lo, H1hi, H1lo,
                                       out + LOGITS_, out + LOGITS_ + BH_, flags);
  // logits = H1 @ W_out + b_out
  gemm_bf16<1><<<79 * 64, 256, 0, stream>>>(H1hi + BH_, nullptr, WoutT, nullptr,
                                            bout, out, H_, V_, V_, 79, 64);
}